// Round 1
// baseline (531.684 us; speedup 1.0000x reference)
//
#include <hip/hip_runtime.h>
#include <cstdint>
#include <cstddef>

// Problem constants: B=64, T=2048, M=512, P=512
#define ROWS 131072      // B*T
#define NCOLS 512        // M

typedef float  floatx4 __attribute__((ext_vector_type(4)));
typedef short  shortx8 __attribute__((ext_vector_type(8)));

__device__ __forceinline__ short f2bf_rne(float f) {
  unsigned u = __float_as_uint(f);
  unsigned r = u + 0x7FFFu + ((u >> 16) & 1u);
  return (short)(r >> 16);
}

// pack two fp32 -> two bf16 (truncation) in one v_perm_b32
__device__ __forceinline__ unsigned pack_bf_trunc(float lo, float hi) {
  return __builtin_amdgcn_perm(__float_as_uint(hi), __float_as_uint(lo), 0x07060302u);
}

#define GLOAD_LDS16(gptr, lptr)                                                 \
  __builtin_amdgcn_global_load_lds(                                             \
      (const __attribute__((address_space(1))) void*)(gptr),                    \
      (__attribute__((address_space(3))) void*)(lptr), 16, 0, 0)

// ---------------------------------------------------------------------------
// Kernel 1: prep.  blocks 0..127: S[b][n] = ds@W_d + b_wd + b_ud  (fp32)
//                  blocks 128..383: U_T[n][k] = bf16(U_d[k][n])
//                  blocks 384..511: zero d_out (logit accumulator)
// ---------------------------------------------------------------------------
extern "C" __global__ __launch_bounds__(256) void prep_kernel(
    const float* __restrict__ hidden, const float* __restrict__ cell,
    const float* __restrict__ W_d, const float* __restrict__ b_wd,
    const float* __restrict__ U_d, const float* __restrict__ b_ud,
    float* __restrict__ S, short* __restrict__ U_T, float* __restrict__ lzero)
{
  int bx = blockIdx.x, tid = threadIdx.x;
  if (bx < 128) {
    int idx = bx * 256 + tid;          // 0..32767
    int b = idx >> 9, n = idx & 511;
    const float* h = hidden + b * 512;
    const float* c = cell   + b * 512;
    float acc = b_wd[n] + b_ud[n];
    for (int k = 0; k < 512; ++k) acc = fmaf(h[k], W_d[k * 512 + n], acc);
    for (int k = 0; k < 512; ++k) acc = fmaf(c[k], W_d[(k + 512) * 512 + n], acc);
    S[idx] = acc;
  } else if (bx < 384) {
    int idx = (bx - 128) * 1024 + tid * 4;   // element index in U_T (n*512+k)
    int n = idx >> 9, k0 = idx & 511;
    unsigned lo = (unsigned short)f2bf_rne(U_d[(size_t)(k0 + 0) * 512 + n]) |
                  ((unsigned)(unsigned short)f2bf_rne(U_d[(size_t)(k0 + 1) * 512 + n]) << 16);
    unsigned hi = (unsigned short)f2bf_rne(U_d[(size_t)(k0 + 2) * 512 + n]) |
                  ((unsigned)(unsigned short)f2bf_rne(U_d[(size_t)(k0 + 3) * 512 + n]) << 16);
    uint2 w; w.x = lo; w.y = hi;
    *(uint2*)(U_T + idx) = w;
  } else {
    int idx = ((bx - 384) * 256 + tid) * 4;
    floatx4 z = {0.f, 0.f, 0.f, 0.f};
    *(floatx4*)(lzero + idx) = z;
  }
}

// ---------------------------------------------------------------------------
// Kernel 2: fused GEMM + tanh + dot(v) -> atomicAdd partial logits
// A = encoder_h (ROWS x 512) fp32, B = U_T (512n x 512k) bf16.
// 128x128 tile / block, 4 waves (2x2 of 64x64), mfma 16x16x32 bf16, BK=32.
// A staged fp32 via global_load_lds with 16B-granule XOR swizzle (source-
// address permute); converted to bf16 at fragment read via v_perm.
// ---------------------------------------------------------------------------
extern "C" __global__ __launch_bounds__(256) void attn_gemm(
    const float* __restrict__ A, const short* __restrict__ UT,
    const float* __restrict__ S, const float* __restrict__ vd,
    float* __restrict__ lout)
{
  __shared__ float Asw[128 * 32];   // 16 KB, swizzled [m][p_phys] 16B granules
  __shared__ short Bs[128 * 32];    // 8 KB, [n][k]

  const int tid = threadIdx.x;
  const int bx  = blockIdx.x;
  // XCD swizzle: the 4 col-blocks of a row-block land consecutively on one XCD
  const int xcd = bx & 7;
  const int k7  = bx >> 3;
  const int rb  = xcd * 128 + (k7 >> 2);
  const int cb  = k7 & 3;
  const int row0 = rb * 128;
  const int col0 = cb * 128;
  const int wave = tid >> 6;
  const int lane = tid & 63;
  const int wr = wave >> 1, wc = wave & 1;
  const int q = lane >> 4, l15 = lane & 15;

  // staging source pointers (advance by kk each iter)
  const float* asrc[4];
#pragma unroll
  for (int j = 0; j < 4; ++j) {
    int c = wave * 4 + j;                  // chunk 0..15 (1 KB each)
    int m = c * 8 + (lane >> 3);           // LDS row this lane's 16B lands in
    int pl = (lane & 7) ^ (m & 7);         // logical 16B position (source)
    asrc[j] = A + (size_t)(row0 + m) * 512 + pl * 4;
  }
  const short* bsrc[2];
#pragma unroll
  for (int j = 0; j < 2; ++j) {
    int c = wave * 2 + j;                  // chunk 0..7 (1 KB each)
    int n = c * 16 + (lane >> 2);
    int ks = (lane & 3) * 8;
    bsrc[j] = UT + (size_t)(col0 + n) * 512 + ks;
  }

  // iteration-invariant fragment LDS offsets
  int aoff0[4], aoff1[4], boff[4];
#pragma unroll
  for (int t = 0; t < 4; ++t) {
    int m = wr * 64 + t * 16 + l15;
    int s = m & 7;
    aoff0[t] = m * 32 + (((2 * q) ^ s) << 2);        // float index
    aoff1[t] = m * 32 + ((((2 * q) | 1) ^ s) << 2);
    int n = wc * 64 + t * 16 + l15;
    boff[t] = n * 32 + q * 8;                         // short index
  }

  floatx4 acc[4][4];
#pragma unroll
  for (int i = 0; i < 4; ++i)
#pragma unroll
    for (int j = 0; j < 4; ++j)
      acc[i][j] = (floatx4){0.f, 0.f, 0.f, 0.f};

  for (int kk = 0; kk < 512; kk += 32) {
    __syncthreads();   // prior iter's ds_reads done before overwrite
#pragma unroll
    for (int j = 0; j < 4; ++j)
      GLOAD_LDS16(asrc[j] + kk, &Asw[(wave * 4 + j) * 256]);
#pragma unroll
    for (int j = 0; j < 2; ++j)
      GLOAD_LDS16(bsrc[j] + kk, &Bs[(wave * 2 + j) * 512]);
    __syncthreads();   // implicit vmcnt(0): LDS tiles ready

    shortx8 af[4], bf[4];
#pragma unroll
    for (int t = 0; t < 4; ++t) {
      floatx4 a0 = *(const floatx4*)(Asw + aoff0[t]);
      floatx4 a1 = *(const floatx4*)(Asw + aoff1[t]);
      union { shortx8 v; unsigned u[4]; } fu;
      fu.u[0] = pack_bf_trunc(a0.x, a0.y);
      fu.u[1] = pack_bf_trunc(a0.z, a0.w);
      fu.u[2] = pack_bf_trunc(a1.x, a1.y);
      fu.u[3] = pack_bf_trunc(a1.z, a1.w);
      af[t] = fu.v;
      bf[t] = *(const shortx8*)(Bs + boff[t]);
    }
#pragma unroll
    for (int tr = 0; tr < 4; ++tr)
#pragma unroll
      for (int tc = 0; tc < 4; ++tc)
        acc[tr][tc] = __builtin_amdgcn_mfma_f32_16x16x32_bf16(
            af[tr], bf[tc], acc[tr][tc], 0, 0, 0);
  }

  // epilogue: e = tanh(acc + S[b][n]); partial = sum_n e*v[n]; atomicAdd rows
  const int bb = row0 >> 11;               // 2048 % 128 == 0 -> one batch/block
  const float* Srow = S + bb * 512;
#pragma unroll
  for (int tr = 0; tr < 4; ++tr) {
#pragma unroll
    for (int r = 0; r < 4; ++r) {
      float ssum = 0.f;
#pragma unroll
      for (int tc = 0; tc < 4; ++tc) {
        int n = col0 + wc * 64 + tc * 16 + l15;
        float x = acc[tr][tc][r] + Srow[n];
        x = fminf(15.f, fmaxf(-15.f, x));
        float e2 = __expf(2.f * x);
        float e = (e2 - 1.f) / (e2 + 1.f);  // tanh
        ssum += e * vd[n];
      }
      ssum += __shfl_xor(ssum, 1);
      ssum += __shfl_xor(ssum, 2);
      ssum += __shfl_xor(ssum, 4);
      ssum += __shfl_xor(ssum, 8);
      if (l15 == 0) {
        int row = row0 + wr * 64 + tr * 16 + q * 4 + r;
        atomicAdd(lout + row, ssum);
      }
    }
  }
}

// ---------------------------------------------------------------------------
// Kernel 3: softmax over T=2048, in place on d_out. One block per batch.
// ---------------------------------------------------------------------------
extern "C" __global__ __launch_bounds__(256) void softmax_t(float* __restrict__ l)
{
  int b = blockIdx.x, tid = threadIdx.x;
  int wave = tid >> 6, lane = tid & 63;
  float* row = l + (size_t)b * 2048;
  float v[8];
  float mx = -3.4e38f;
#pragma unroll
  for (int i = 0; i < 8; ++i) { v[i] = row[tid + i * 256]; mx = fmaxf(mx, v[i]); }
#pragma unroll
  for (int m = 1; m < 64; m <<= 1) mx = fmaxf(mx, __shfl_xor(mx, m));
  __shared__ float red[8];
  if (lane == 0) red[wave] = mx;
  __syncthreads();
  mx = fmaxf(fmaxf(red[0], red[1]), fmaxf(red[2], red[3]));
  float s = 0.f;
#pragma unroll
  for (int i = 0; i < 8; ++i) { v[i] = __expf(v[i] - mx); s += v[i]; }
#pragma unroll
  for (int m = 1; m < 64; m <<= 1) s += __shfl_xor(s, m);
  if (lane == 0) red[4 + wave] = s;
  __syncthreads();
  s = red[4] + red[5] + red[6] + red[7];
  float inv = 1.f / s;
#pragma unroll
  for (int i = 0; i < 8; ++i) row[tid + i * 256] = v[i] * inv;
}

// ---------------------------------------------------------------------------
extern "C" void kernel_launch(void* const* d_in, const int* in_sizes, int n_in,
                              void* d_out, int out_size, void* d_ws, size_t ws_size,
                              hipStream_t stream) {
  const float* hidden = (const float*)d_in[0];
  const float* cell   = (const float*)d_in[1];
  const float* enc    = (const float*)d_in[2];
  const float* W_d    = (const float*)d_in[3];
  const float* b_wd   = (const float*)d_in[4];
  const float* U_d    = (const float*)d_in[5];
  const float* b_ud   = (const float*)d_in[6];
  const float* v_d    = (const float*)d_in[7];
  // d_in[8] = b_vd: constant shift over T -> softmax-invariant, unused.
  float* out = (float*)d_out;                     // logits then softmax, in place
  float* S   = (float*)d_ws;                      // 64*512 fp32   = 128 KB
  short* UT  = (short*)((char*)d_ws + 32768 * sizeof(float));  // 512*512 bf16 = 512 KB

  hipLaunchKernelGGL(prep_kernel, dim3(512), dim3(256), 0, stream,
                     hidden, cell, W_d, b_wd, U_d, b_ud, S, UT, out);
  hipLaunchKernelGGL(attn_gemm, dim3(4096), dim3(256), 0, stream,
                     enc, UT, S, v_d, out);
  hipLaunchKernelGGL(softmax_t, dim3(64), dim3(256), 0, stream, out);
}